// Round 1
// baseline (58.513 us; speedup 1.0000x reference)
//
#include <hip/hip_runtime.h>

// Problem constants (B, C, O, K, H, W) = (8, 64, 64, 3, 128, 128)
#define NTAP 9
#define C_DIM 64
#define O_DIM 64
#define HW 128
#define CPAD 72   // 64 c + 8 pad -> row stride 144B (kills the 32-way LDS bank conflict)

typedef short s16x8 __attribute__((ext_vector_type(8)));
typedef float f32x16 __attribute__((ext_vector_type(16)));

__device__ __forceinline__ unsigned short f2bf(float x) {
    // round-to-nearest-even float -> bf16 bits
    unsigned int u = __float_as_uint(x);
    unsigned int r = (u + 0x7fffu + ((u >> 16) & 1u)) >> 16;
    return (unsigned short)r;
}

// ---------------------------------------------------------------------------
// Pre-kernel: W [C=64][3][3][O=64] f32  ->  fragment-major bf16 in d_ws.
// Fragment F = ((tap*4 + s)*2 + m)*64 + lane holds 8 bf16 (16B) for lane:
//   element e:  c = 16*s + 8*(lane>>5) + e,   o = 32*m + (lane&31)
// The SAME (lane/32, e) -> k-slot mapping is used for the B (feat) operand,
// so the MFMA contraction is correct for any hardware k-slot permutation.
// ---------------------------------------------------------------------------
__global__ void swizzle_W_kernel(const float* __restrict__ W,
                                 unsigned short* __restrict__ Wf) {
    int idx = blockIdx.x * 256 + threadIdx.x;
    if (idx >= NTAP * 4 * 2 * 64 * 8) return;   // 36864 bf16 = 73728 B
    int e    = idx & 7;
    int lane = (idx >> 3) & 63;
    int m    = (idx >> 9) & 1;
    int s    = (idx >> 10) & 3;
    int tap  = idx >> 12;                        // 0..8
    int c = s * 16 + ((lane >> 5) << 3) + e;     // 0..63
    int o = (m << 5) + (lane & 31);              // 0..63
    // W flat index: c*3*3*64 + tap*64 + o
    Wf[idx] = f2bf(W[c * 576 + tap * 64 + o]);
}

// ---------------------------------------------------------------------------
// Main kernel: one block per (batch b, image row h). Out tile = 64 o x 128 w.
// out[o][w] = sum_tap tm[tap][w] * ( W_tap^T (64x64) . feat_row(h-1+tap/3, +tap%3) )
// 4 waves: wave = 32 w-columns, all 64 o (2 x f32x16 accumulators).
// ---------------------------------------------------------------------------
__global__ __launch_bounds__(256) void dyconv_kernel(
    const float* __restrict__ feat, const float* __restrict__ tm,
    const unsigned short* __restrict__ Wf, float* __restrict__ out)
{
    __shared__ __align__(16) unsigned short feat_lds[3][HW + 2][CPAD];

    const int h   = blockIdx.x;
    const int b   = blockIdx.y;
    const int tid = threadIdx.x;

    // ---- stage feat rows h-1..h+1 (bf16, transposed to [r][w+1][c]) ----
    {
        const int w     = tid & 127;   // coalesced along w for global reads
        const int chalf = tid >> 7;    // threads 0-127: c 0..31, 128-255: c 32..63
        for (int r = 0; r < 3; ++r) {
            const int hr = h + r - 1;
            const bool inb = (hr >= 0) && (hr < HW);
            const float* src = feat + (((size_t)b * C_DIM) * HW + hr) * HW + w;
            for (int cp = chalf * 16; cp < chalf * 16 + 16; ++cp) {
                const int c0 = cp * 2;
                float v0 = 0.f, v1 = 0.f;
                if (inb) {
                    v0 = src[(size_t)c0 * (HW * HW)];
                    v1 = src[(size_t)(c0 + 1) * (HW * HW)];
                }
                unsigned int pk = (unsigned int)f2bf(v0) |
                                  ((unsigned int)f2bf(v1) << 16);
                *(unsigned int*)&feat_lds[r][w + 1][c0] = pk;
            }
        }
        // zero the left/right halo columns (image boundary zero-padding)
        if (tid < 128) {
            const int c  = tid & 63;
            const int wi = (tid >> 6) ? (HW + 1) : 0;
            for (int r = 0; r < 3; ++r) feat_lds[r][wi][c] = 0;
        }
    }

    const int lane = tid & 63;
    const int wave = tid >> 6;
    const int g    = lane >> 5;            // k-slot half
    const int wcol = wave * 32 + (lane & 31);   // this lane's output column (D col = lane&31)

    // prefetch the 9 tm scalars for this lane's column (L2/L3 resident)
    float tmr[NTAP];
    #pragma unroll
    for (int t = 0; t < NTAP; ++t)
        tmr[t] = tm[((size_t)b * NTAP + t) * (HW * HW) + (size_t)h * HW + wcol];

    __syncthreads();

    const s16x8* __restrict__ Wf8 = (const s16x8*)Wf;

    f32x16 acc0 = {0,0,0,0,0,0,0,0,0,0,0,0,0,0,0,0};
    f32x16 acc1 = acc0;

    #pragma unroll
    for (int tap = 0; tap < NTAP; ++tap) {
        const int di = tap / 3;            // row offset (const-folded)
        const int dj = tap % 3;            // col shift  (const-folded)
        // B operand row: feat_lds[di][w + dj][.], 16B-aligned (stride 144B)
        const s16x8* bp = (const s16x8*)&feat_lds[di][wcol + dj][0];

        f32x16 pa = {0,0,0,0,0,0,0,0,0,0,0,0,0,0,0,0};
        f32x16 pb = pa;
        #pragma unroll
        for (int s = 0; s < 4; ++s) {      // c chunks of 16
            s16x8 bf = bp[2 * s + g];                                  // ds_read_b128
            s16x8 a0 = Wf8[((tap * 4 + s) * 2 + 0) * 64 + lane];       // L2-hot 16B
            s16x8 a1 = Wf8[((tap * 4 + s) * 2 + 1) * 64 + lane];
            pa = __builtin_amdgcn_mfma_f32_32x32x16_bf16(a0, bf, pa, 0, 0, 0);
            pb = __builtin_amdgcn_mfma_f32_32x32x16_bf16(a1, bf, pb, 0, 0, 0);
        }
        // fold this tap's GEMM into the running accumulator, scaled by tm[tap][w]
        const float tv = tmr[tap];
        #pragma unroll
        for (int r = 0; r < 16; ++r) {
            acc0[r] = fmaf(tv, pa[r], acc0[r]);
            acc1[r] = fmaf(tv, pb[r], acc1[r]);
        }
    }

    // ---- store: D layout (32x32): col = lane&31, row = (r&3)+8*(r>>2)+4*g ----
    float* op = out + ((size_t)b * O_DIM) * (HW * HW) + (size_t)h * HW + wcol;
    #pragma unroll
    for (int r = 0; r < 16; ++r) {
        const int o = (r & 3) + ((r >> 2) << 3) + (g << 2);
        op[(size_t)o        * (HW * HW)] = acc0[r];
        op[(size_t)(o + 32) * (HW * HW)] = acc1[r];
    }
}

extern "C" void kernel_launch(void* const* d_in, const int* in_sizes, int n_in,
                              void* d_out, int out_size, void* d_ws, size_t ws_size,
                              hipStream_t stream) {
    const float* feat = (const float*)d_in[0];   // [8,64,128,128] f32
    const float* tm   = (const float*)d_in[1];   // [8,9,16384]    f32
    const float* W    = (const float*)d_in[2];   // [64,3,3,64]    f32
    float* out        = (float*)d_out;           // [8,64,128,128] f32
    unsigned short* Wf = (unsigned short*)d_ws;  // needs 73728 B of scratch

    swizzle_W_kernel<<<dim3(144), dim3(256), 0, stream>>>(W, Wf);
    dyconv_kernel<<<dim3(HW, 8), dim3(256), 0, stream>>>(feat, tm, Wf, out);
}

// Round 2
// 33.098 us; speedup vs baseline: 1.7678x; 1.7678x over previous
//
#include <hip/hip_runtime.h>

// Problem constants (B, C, O, K, H, W) = (8, 64, 64, 3, 128, 128)
#define NTAP 9
#define C_DIM 64
#define O_DIM 64
#define HW 128
#define CPAD 72   // row stride 144B: 16B-aligned, 4-way bank pattern on b128 ops

typedef short s16x8 __attribute__((ext_vector_type(8)));
typedef float f32x16 __attribute__((ext_vector_type(16)));

__device__ __forceinline__ unsigned short f2bf(float x) {
    unsigned int u = __float_as_uint(x);
    unsigned int r = (u + 0x7fffu + ((u >> 16) & 1u)) >> 16;
    return (unsigned short)r;
}

// ---------------------------------------------------------------------------
// Pre-kernel: W [C=64][3][3][O=64] f32 -> fragment-major bf16 (d_ws, 72KB).
// Fragment F = ((tap*4 + s)*2 + m)*64 + lane, element e:
//   c = 16*s + 8*(lane>>5) + e,   o = 32*m + (lane&31)
// Same (lane>>5, e) -> k-slot mapping is used for the feat (B) operand, so the
// contraction is correct under any hardware k-slot permutation.
// ---------------------------------------------------------------------------
__global__ void swizzle_W_kernel(const float* __restrict__ W,
                                 unsigned short* __restrict__ Wf) {
    int idx = blockIdx.x * 256 + threadIdx.x;
    if (idx >= NTAP * 4 * 2 * 64 * 8) return;
    int e    = idx & 7;
    int lane = (idx >> 3) & 63;
    int m    = (idx >> 9) & 1;
    int s    = (idx >> 10) & 3;
    int tap  = idx >> 12;
    int c = s * 16 + ((lane >> 5) << 3) + e;
    int o = (m << 5) + (lane & 31);
    Wf[idx] = f2bf(W[c * 576 + tap * 64 + o]);
}

// ---------------------------------------------------------------------------
// Main kernel: one block per (batch b, h-pair). 512 threads = 8 waves.
// Block output: 64 o x 128 w x 2 h. Stages 4 input rows (h0-1 .. h0+2) as
// bf16 [4][130][72] in LDS (74880 B -> 2 blocks/CU, 16 waves/CU).
// Wave w: output row h0 + (w>>2), columns (w&3)*32 .. +31, all 64 o.
// ---------------------------------------------------------------------------
__global__ __launch_bounds__(512) void dyconv_kernel(
    const float* __restrict__ feat, const float* __restrict__ tm,
    const unsigned short* __restrict__ Wf, float* __restrict__ out)
{
    __shared__ __align__(16) unsigned short feat_lds[4][HW + 2][CPAD];

    // ---- bijective XCD swizzle: XCD x owns batch x (contiguous h range) ----
    const int flat = blockIdx.x;                 // 0..511
    const int work = (flat & 7) * 64 + (flat >> 3);
    const int b    = work >> 6;                  // 0..7
    const int h0   = (work & 63) * 2;            // output rows h0, h0+1

    const int tid = threadIdx.x;

    // ---- stage 4 input rows, batched: 16x dwordx4 loads -> 8x b128 writes ----
    {
        const int r   = tid >> 7;                // input row 0..3 (h = h0-1+r)
        const int t7  = tid & 127;
        const int q   = t7 & 3;                  // c-group (bank spread on writes)
        const int wg  = t7 >> 2;                 // w-group: w0 = wg*4
        const int hin = h0 - 1 + r;
        const bool inb = (hin >= 0) && (hin < HW);
        const float* src = feat + (((size_t)b * C_DIM) * HW + hin) * HW + wg * 4;

        float4 v[16];
        #pragma unroll
        for (int half = 0; half < 2; ++half) {
            const int c0 = q * 8 + half * 32;
            #pragma unroll
            for (int j = 0; j < 8; ++j) {
                v[half * 8 + j] = inb
                    ? *(const float4*)(src + (size_t)(c0 + j) * (HW * HW))
                    : float4{0.f, 0.f, 0.f, 0.f};
            }
        }
        #pragma unroll
        for (int half = 0; half < 2; ++half) {
            const int c0 = q * 8 + half * 32;
            #pragma unroll
            for (int i = 0; i < 4; ++i) {        // w = wg*4 + i
                s16x8 pk;
                #pragma unroll
                for (int j = 0; j < 8; ++j) {
                    const float* vf = (const float*)&v[half * 8 + j];
                    pk[j] = (short)f2bf(vf[i]);
                }
                *(s16x8*)&feat_lds[r][wg * 4 + i + 1][c0] = pk;
            }
        }
        // zero left/right halo columns (w = -1 and w = 128)
        const int zr = tid >> 7, zc = tid & 63, zs = (tid >> 6) & 1;
        feat_lds[zr][zs ? (HW + 1) : 0][zc] = 0;
    }

    const int lane = tid & 63;
    const int wave = tid >> 6;                   // 0..7
    const int hrow = wave >> 2;                  // 0/1: output row h0+hrow
    const int colg = wave & 3;
    const int g    = lane >> 5;                  // k-slot half
    const int wcol = colg * 32 + (lane & 31);    // output column (D col = lane&31)
    const int hout = h0 + hrow;

    // prefetch tm scalars (before barrier; independent of LDS)
    float tmr[NTAP];
    #pragma unroll
    for (int t = 0; t < NTAP; ++t)
        tmr[t] = tm[((size_t)b * NTAP + t) * (HW * HW) + (size_t)hout * HW + wcol];

    __syncthreads();

    const s16x8* __restrict__ Wf8 = (const s16x8*)Wf;

    f32x16 acc0 = {0,0,0,0,0,0,0,0,0,0,0,0,0,0,0,0};
    f32x16 acc1 = acc0;

    #pragma unroll
    for (int tap = 0; tap < NTAP; ++tap) {
        const int di = tap / 3;
        const int dj = tap % 3;
        const s16x8* bp = (const s16x8*)&feat_lds[hrow + di][wcol + dj][0];

        f32x16 pa = {0,0,0,0,0,0,0,0,0,0,0,0,0,0,0,0};
        f32x16 pb = pa;
        #pragma unroll
        for (int s = 0; s < 4; ++s) {
            s16x8 bf = bp[2 * s + g];
            s16x8 a0 = Wf8[((tap * 4 + s) * 2 + 0) * 64 + lane];
            s16x8 a1 = Wf8[((tap * 4 + s) * 2 + 1) * 64 + lane];
            pa = __builtin_amdgcn_mfma_f32_32x32x16_bf16(a0, bf, pa, 0, 0, 0);
            pb = __builtin_amdgcn_mfma_f32_32x32x16_bf16(a1, bf, pb, 0, 0, 0);
        }
        const float tv = tmr[tap];
        #pragma unroll
        for (int r = 0; r < 16; ++r) {
            acc0[r] = fmaf(tv, pa[r], acc0[r]);
            acc1[r] = fmaf(tv, pb[r], acc1[r]);
        }
    }

    // ---- store: D (32x32) layout: col = lane&31, row = (r&3)+8*(r>>2)+4*g ----
    float* op = out + ((size_t)b * O_DIM) * (HW * HW) + (size_t)hout * HW + wcol;
    #pragma unroll
    for (int r = 0; r < 16; ++r) {
        const int o = (r & 3) + ((r >> 2) << 3) + (g << 2);
        op[(size_t)o        * (HW * HW)] = acc0[r];
        op[(size_t)(o + 32) * (HW * HW)] = acc1[r];
    }
}

extern "C" void kernel_launch(void* const* d_in, const int* in_sizes, int n_in,
                              void* d_out, int out_size, void* d_ws, size_t ws_size,
                              hipStream_t stream) {
    const float* feat = (const float*)d_in[0];   // [8,64,128,128] f32
    const float* tm   = (const float*)d_in[1];   // [8,9,16384]    f32
    const float* W    = (const float*)d_in[2];   // [64,3,3,64]    f32
    float* out        = (float*)d_out;           // [8,64,128,128] f32
    unsigned short* Wf = (unsigned short*)d_ws;  // 73728 B scratch

    swizzle_W_kernel<<<dim3(144), dim3(256), 0, stream>>>(W, Wf);
    dyconv_kernel<<<dim3(512), dim3(512), 0, stream>>>(feat, tm, Wf, out);
}